// Round 4
// baseline (541.478 us; speedup 1.0000x reference)
//
#include <hip/hip_runtime.h>
#include <math.h>

// Problem constants (from reference setup_inputs):
//   x:      (32, 8, 512, 512) fp32
//   weight: (16, 8, 3, 3)     fp32
//   bias:   (16, 1, 1)        fp32
//   out:    (32,)             fp32
//
// Math: full conv-transpose + global mean pool collapses to
//   pooled[n,co] = (Σ_hw x[n,ci,·]) · (Σ_kk w[co,ci,·]) / (514*514) + bias[co]
//   out[n] = logsumexp_co(pooled[n,:]) * 10
// x is read exactly once (268.4 MB) -> strictly HBM-read-bound.
// Single fused kernel: per-block partial sums + last-block finalize
// (device-scope atomic counter, release/acquire threadfence).

#define B_          32
#define CIN_        8
#define COUT_       16
#define PLANES      (B_ * CIN_)          // 256
#define PLANE_F4    (512 * 512 / 4)      // 65536 float4 per (n,ci) plane
#define BLOCKS_PER_PLANE 16
#define NBLOCKS     (PLANES * BLOCKS_PER_PLANE)   // 4096
#define THREADS     256
#define F4_PER_THREAD 16                 // 256 thr * 16 f4 * 16 blocks = plane

// Native vector type: __builtin_nontemporal_load requires a non-class vector.
typedef float nfloat4 __attribute__((ext_vector_type(4)));

__global__ __launch_bounds__(THREADS)
void fused_reduce(const float* __restrict__ x,
                  const float* __restrict__ weight,
                  const float* __restrict__ bias,
                  float* __restrict__ out,
                  float* __restrict__ partials,
                  unsigned int* __restrict__ counter) {
    const int b     = blockIdx.x;
    const int plane = b >> 4;            // / BLOCKS_PER_PLANE
    const int part  = b & 15;
    const nfloat4* p = reinterpret_cast<const nfloat4*>(x)
                     + (size_t)plane * PLANE_F4
                     + (size_t)part * (THREADS * F4_PER_THREAD);
    const int tid = threadIdx.x;

    // 4 independent accumulators -> deep outstanding-load window.
    float a0 = 0.f, a1 = 0.f, a2 = 0.f, a3 = 0.f;
#pragma unroll
    for (int i = 0; i < F4_PER_THREAD; i += 4) {
        nfloat4 v0 = __builtin_nontemporal_load(&p[tid + (i + 0) * THREADS]);
        nfloat4 v1 = __builtin_nontemporal_load(&p[tid + (i + 1) * THREADS]);
        nfloat4 v2 = __builtin_nontemporal_load(&p[tid + (i + 2) * THREADS]);
        nfloat4 v3 = __builtin_nontemporal_load(&p[tid + (i + 3) * THREADS]);
        a0 += (v0.x + v0.y) + (v0.z + v0.w);
        a1 += (v1.x + v1.y) + (v1.z + v1.w);
        a2 += (v2.x + v2.y) + (v2.z + v2.w);
        a3 += (v3.x + v3.y) + (v3.z + v3.w);
    }
    float s = (a0 + a1) + (a2 + a3);

    // wave64 shuffle reduction
#pragma unroll
    for (int off = 32; off > 0; off >>= 1)
        s += __shfl_down(s, off, 64);

    __shared__ float wsum[THREADS / 64];
    __shared__ int   is_last;
    const int wave = tid >> 6;
    if ((tid & 63) == 0) wsum[wave] = s;
    __syncthreads();
    if (tid == 0) {
        partials[b] = (wsum[0] + wsum[1]) + (wsum[2] + wsum[3]);
        __threadfence();                               // release
        unsigned int old = atomicAdd(counter, 1u);     // device-scope
        is_last = (old == NBLOCKS - 1);
    }
    __syncthreads();
    if (!is_last) return;

    // ---- last block: finalize ----
    __threadfence();                                   // acquire

    __shared__ float sx[PLANES];          // [n][ci] = n*8+ci
    __shared__ float sw[COUT_ * CIN_];    // [co][ci] = co*8+ci
    __shared__ float pooled[B_ * COUT_];  // [n][co] = n*16+co

    // Per-plane total: sum this plane's 16 block partials.
    {
        float t = 0.0f;
        const float* pp = partials + tid * BLOCKS_PER_PLANE;
#pragma unroll
        for (int i = 0; i < BLOCKS_PER_PLANE; ++i) t += pp[i];
        sx[tid] = t;
    }
    // Kernel-tap sums: Sw[co][ci] = Σ over 3x3 taps.
    if (tid < COUT_ * CIN_) {
        const float* wp = weight + tid * 9;
        float t = 0.0f;
#pragma unroll
        for (int i = 0; i < 9; ++i) t += wp[i];
        sw[tid] = t;
    }
    __syncthreads();

    const float inv_area = 1.0f / (514.0f * 514.0f);
#pragma unroll
    for (int r = 0; r < 2; ++r) {
        const int idx = tid + r * 256;    // [n][co], 512 total
        const int n  = idx >> 4;
        const int co = idx & 15;
        float acc = 0.0f;
#pragma unroll
        for (int ci = 0; ci < CIN_; ++ci)
            acc += sx[n * CIN_ + ci] * sw[co * CIN_ + ci];
        pooled[idx] = acc * inv_area + bias[co];
    }
    __syncthreads();

    if (tid < B_) {
        float m = -INFINITY;
#pragma unroll
        for (int co = 0; co < COUT_; ++co)
            m = fmaxf(m, pooled[tid * COUT_ + co]);
        float t = 0.0f;
#pragma unroll
        for (int co = 0; co < COUT_; ++co)
            t += __expf(pooled[tid * COUT_ + co] - m);
        out[tid] = (m + __logf(t)) * 10.0f;
    }
}

extern "C" void kernel_launch(void* const* d_in, const int* in_sizes, int n_in,
                              void* d_out, int out_size, void* d_ws, size_t ws_size,
                              hipStream_t stream) {
    const float* x      = (const float*)d_in[0];
    const float* weight = (const float*)d_in[1];
    const float* bias   = (const float*)d_in[2];
    float* out          = (float*)d_out;
    float* partials     = (float*)d_ws;                       // 4096 floats
    unsigned int* counter = (unsigned int*)((char*)d_ws + NBLOCKS * sizeof(float));

    // Counter must be 0 every call (ws is re-poisoned to 0xAA by the harness).
    hipMemsetAsync(counter, 0, sizeof(unsigned int), stream);
    fused_reduce<<<NBLOCKS, THREADS, 0, stream>>>(x, weight, bias, out,
                                                  partials, counter);
}

// Round 5
// 330.072 us; speedup vs baseline: 1.6405x; 1.6405x over previous
//
#include <hip/hip_runtime.h>
#include <math.h>

// Problem constants (from reference setup_inputs):
//   x:      (32, 8, 512, 512) fp32
//   weight: (16, 8, 3, 3)     fp32
//   bias:   (16, 1, 1)        fp32
//   out:    (32,)             fp32
//
// Math: full conv-transpose + global mean pool collapses to
//   pooled[n,co] = (Σ_hw x[n,ci,·]) · (Σ_kk w[co,ci,·]) / (514*514) + bias[co]
//   out[n] = logsumexp_co(pooled[n,:]) * 10
// x is read exactly once (268.4 MB) -> strictly HBM-read-bound, floor ~42 µs.
//
// R4 post-mortem: fused last-block-finalize (threadfence + global atomic per
// block) cost ~250 µs of coherence serialization on 8 XCDs — reverted to the
// two-kernel structure, which measured ~43 µs total (~6.2 TB/s, 98% of the
// achievable HBM ceiling).

#define B_          32
#define CIN_        8
#define COUT_       16
#define PLANES      (B_ * CIN_)          // 256
#define PLANE_F4    (512 * 512 / 4)      // 65536 float4 per (n,ci) plane
#define BLOCKS_PER_PLANE 8
#define THREADS     256
#define F4_PER_THREAD 32                 // 256 thr * 32 f4 = 8192 f4/block * 8 = plane

// Native vector type: __builtin_nontemporal_load requires a non-class vector.
typedef float nfloat4 __attribute__((ext_vector_type(4)));

__global__ __launch_bounds__(THREADS)
void reduce_planes(const float* __restrict__ x, float* __restrict__ partials) {
    const int b     = blockIdx.x;
    const int plane = b >> 3;            // / BLOCKS_PER_PLANE
    const int part  = b & 7;
    const nfloat4* p = reinterpret_cast<const nfloat4*>(x)
                     + (size_t)plane * PLANE_F4
                     + (size_t)part * (THREADS * F4_PER_THREAD);
    const int tid = threadIdx.x;

    // 4 independent accumulators -> deep outstanding-load window.
    float a0 = 0.f, a1 = 0.f, a2 = 0.f, a3 = 0.f;
#pragma unroll
    for (int i = 0; i < F4_PER_THREAD; i += 4) {
        nfloat4 v0 = __builtin_nontemporal_load(&p[tid + (i + 0) * THREADS]);
        nfloat4 v1 = __builtin_nontemporal_load(&p[tid + (i + 1) * THREADS]);
        nfloat4 v2 = __builtin_nontemporal_load(&p[tid + (i + 2) * THREADS]);
        nfloat4 v3 = __builtin_nontemporal_load(&p[tid + (i + 3) * THREADS]);
        a0 += (v0.x + v0.y) + (v0.z + v0.w);
        a1 += (v1.x + v1.y) + (v1.z + v1.w);
        a2 += (v2.x + v2.y) + (v2.z + v2.w);
        a3 += (v3.x + v3.y) + (v3.z + v3.w);
    }
    float s = (a0 + a1) + (a2 + a3);

    // wave64 shuffle reduction
#pragma unroll
    for (int off = 32; off > 0; off >>= 1)
        s += __shfl_down(s, off, 64);

    __shared__ float ws[THREADS / 64];
    const int wave = tid >> 6;
    if ((tid & 63) == 0) ws[wave] = s;
    __syncthreads();
    if (tid == 0)
        partials[b] = (ws[0] + ws[1]) + (ws[2] + ws[3]);
}

__global__ __launch_bounds__(256)
void finalize(const float* __restrict__ partials,
              const float* __restrict__ weight,
              const float* __restrict__ bias,
              float* __restrict__ out) {
    __shared__ float sx[PLANES];          // [n][ci] = n*8+ci
    __shared__ float sw[COUT_ * CIN_];    // [co][ci] = co*8+ci
    __shared__ float pooled[B_ * COUT_];  // [n][co] = n*16+co
    const int tid = threadIdx.x;

    // Per-plane total: sum this plane's 8 block partials.
    {
        float s = 0.0f;
        const float* pp = partials + tid * BLOCKS_PER_PLANE;
#pragma unroll
        for (int i = 0; i < BLOCKS_PER_PLANE; ++i) s += pp[i];
        sx[tid] = s;
    }
    // Kernel-tap sums: Sw[co][ci] = Σ over 3x3 taps.
    if (tid < COUT_ * CIN_) {
        const float* wp = weight + tid * 9;
        float s = 0.0f;
#pragma unroll
        for (int i = 0; i < 9; ++i) s += wp[i];
        sw[tid] = s;
    }
    __syncthreads();

    const float inv_area = 1.0f / (514.0f * 514.0f);
#pragma unroll
    for (int r = 0; r < 2; ++r) {
        const int idx = tid + r * 256;    // [n][co], 512 total
        const int n  = idx >> 4;
        const int co = idx & 15;
        float acc = 0.0f;
#pragma unroll
        for (int ci = 0; ci < CIN_; ++ci)
            acc += sx[n * CIN_ + ci] * sw[co * CIN_ + ci];
        pooled[idx] = acc * inv_area + bias[co];
    }
    __syncthreads();

    if (tid < B_) {
        float m = -INFINITY;
#pragma unroll
        for (int co = 0; co < COUT_; ++co)
            m = fmaxf(m, pooled[tid * COUT_ + co]);
        float s = 0.0f;
#pragma unroll
        for (int co = 0; co < COUT_; ++co)
            s += __expf(pooled[tid * COUT_ + co] - m);
        out[tid] = (m + __logf(s)) * 10.0f;
    }
}

extern "C" void kernel_launch(void* const* d_in, const int* in_sizes, int n_in,
                              void* d_out, int out_size, void* d_ws, size_t ws_size,
                              hipStream_t stream) {
    const float* x      = (const float*)d_in[0];
    const float* weight = (const float*)d_in[1];
    const float* bias   = (const float*)d_in[2];
    float* out          = (float*)d_out;
    float* partials     = (float*)d_ws;   // 2048 floats = 8 KB of scratch

    reduce_planes<<<PLANES * BLOCKS_PER_PLANE, THREADS, 0, stream>>>(x, partials);
    finalize<<<1, 256, 0, stream>>>(partials, weight, bias, out);
}